// Round 13
// baseline (4031.786 us; speedup 1.0000x reference)
//
#include <hip/hip_runtime.h>

#define B_ 16
#define S_ 4096
#define D_ 256
#define H_ 256

typedef _Float16 h2 __attribute__((ext_vector_type(2)));
typedef _Float16 h8v __attribute__((ext_vector_type(8)));
typedef float f4 __attribute__((ext_vector_type(4)));

static __device__ __forceinline__ float fdot2f(h2 a, h2 b, float c) {
    return __builtin_amdgcn_fdot2(a, b, c, false);
}

template <int CTRL>
static __device__ __forceinline__ float dpp_mv(float v) {
    int r = __builtin_amdgcn_update_dpp(0, __float_as_int(v), CTRL, 0xF, 0xF, true);
    return __int_as_float(r);
}
#define DPP_XOR1  0xB1    // quad_perm [1,0,3,2]  : lane ^ 1
#define DPP_XOR2  0x4E    // quad_perm [2,3,0,1]  : lane ^ 2
#define DPP_HMIRR 0x141   // row_half_mirror      : lane -> 7-(l&7) in 8-group

// LDS-only barrier (T4): drain lgkmcnt, leave global store/load in flight.
static __device__ __forceinline__ void lds_barrier() {
    asm volatile("s_waitcnt lgkmcnt(0)" ::: "memory");
    __builtin_amdgcn_s_barrier();
}

// Kernel 1: xp[row][h] = sum_d x[row][d] * Wx[d][h] + bias[h], into d_out.
__global__ __launch_bounds__(256) void xproj_kernel(
    const float* __restrict__ x, const float* __restrict__ Wx,
    const float* __restrict__ bias, float* __restrict__ out)
{
    __shared__ float xs[32 * 256];
    const int tid = threadIdx.x;
    const long long row0 = (long long)blockIdx.x * 32;

    {
        const f4* __restrict__ xg = (const f4*)(x + row0 * D_);
        f4* xsv = (f4*)xs;
        #pragma unroll
        for (int k = 0; k < 8; ++k)
            xsv[tid + k * 256] = xg[tid + k * 256];
    }
    __syncthreads();

    const int j = tid;
    float acc[32];
    const float bj = bias[j];
    #pragma unroll
    for (int r = 0; r < 32; ++r) acc[r] = bj;

    for (int d4 = 0; d4 < D_ / 4; ++d4) {
        const float w0 = Wx[(d4 * 4 + 0) * H_ + j];
        const float w1 = Wx[(d4 * 4 + 1) * H_ + j];
        const float w2 = Wx[(d4 * 4 + 2) * H_ + j];
        const float w3 = Wx[(d4 * 4 + 3) * H_ + j];
        #pragma unroll
        for (int r = 0; r < 32; ++r) {
            f4 xv = *(const f4*)&xs[r * 256 + d4 * 4];
            acc[r] = fmaf(xv.x, w0, acc[r]);
            acc[r] = fmaf(xv.y, w1, acc[r]);
            acc[r] = fmaf(xv.z, w2, acc[r]);
            acc[r] = fmaf(xv.w, w3, acc[r]);
        }
    }
    #pragma unroll
    for (int r = 0; r < 32; ++r)
        out[(row0 + r) * H_ + j] = acc[r];
}

// Kernel 2: HYBRID scan — MFMA pipe and VALU pipe work concurrently in every
// wave. One block (CU) per batch, 256 threads (4 waves, 1/SIMD).
// Wave w: cols [64w,64w+32) via replicated-row MFMA (2 N-tiles, 16 MFMA,
//         R11-verified frag convention), owner lanes kg<2 (j=64w+16kg+lc);
//         cols [64w+32,64w+64) via dot2 (lane: group g3=l>>3 -> 4 cols,
//         slice sl3=l&7 -> 32 k's; 64 dot2), reduced by pure-DPP butterfly
//         {half_mirror, ^2, ^1}; owner = even sl3, col = 64w+32+4g3+2b2+b1.
// h double-buffered linear in LDS; lgkm-only barrier per step.
__global__ __launch_bounds__(256, 1) void scan_kernel(
    const float* __restrict__ Wh, const float* __restrict__ state0,
    float* __restrict__ out)
{
    __shared__ __align__(16) _Float16 h_lds[2][H_];
    const int tid = threadIdx.x;
    const int l   = tid & 63;
    const int wav = tid >> 6;        // 0..3
    const int lc  = l & 15;
    const int kg  = l >> 4;          // 0..3
    const int g3  = l >> 3;          // 0..7 (VALU col group)
    const int sl3 = l & 7;           // 0..7 (VALU k slice)
    const int b   = blockIdx.x;

    // ---- MFMA constants: B-frags for 2 N-tiles (R11 convention) ----
    h8v bf[2][8];
    #pragma unroll
    for (int nt = 0; nt < 2; ++nt) {
        const int j = 64 * wav + 16 * nt + lc;
        #pragma unroll
        for (int ks = 0; ks < 8; ++ks) {
            #pragma unroll
            for (int e = 0; e < 8; ++e) {
                const int k = 32 * ks + 8 * kg + e;
                bf[nt][ks][e] = (_Float16)Wh[k * H_ + j];
            }
        }
    }
    const int j_m = 64 * wav + 16 * kg + lc;        // valid owner if kg<2
    const bool own_m = (kg < 2);

    // ---- VALU constants: w_v[jj][p] for 4 cols x 32 k's ----
    const bool b2v = (sl3 & 4) != 0;
    const bool b1v = (sl3 & 2) != 0;
    const int jv_own = 64 * wav + 32 + 4 * g3 + (b2v ? 2 : 0) + (b1v ? 1 : 0);
    const bool own_v = (sl3 & 1) == 0;
    h2 wv[4][16];
    #pragma unroll
    for (int jj = 0; jj < 4; ++jj) {
        const int jv = 64 * wav + 32 + 4 * g3 + jj;
        #pragma unroll
        for (int p = 0; p < 16; ++p) {
            const int k = 32 * sl3 + 2 * p;
            h2 q;
            q[0] = (_Float16)Wh[(long long)k * H_ + jv];
            q[1] = (_Float16)Wh[(long long)(k + 1) * H_ + jv];
            wv[jj][p] = q;
        }
    }

    h_lds[0][tid] = (_Float16)state0[b * H_ + tid];

    float* __restrict__ outb = out + (long long)b * S_ * H_;

    // xp prefetch rings, distance 4 (all lanes load; only owners consume)
    float xrM[4], xrV[4];
    #pragma unroll
    for (int k = 0; k < 4; ++k) {
        xrM[k] = outb[(long long)k * H_ + j_m];
        xrV[k] = outb[(long long)k * H_ + jv_own];
    }
    __syncthreads();

    const int abase = 8 * kg;        // MFMA A-slice offset inside a ks block
    const int vbase = 32 * sl3;      // VALU h-slice offset (f16 index)

    #pragma unroll 2
    for (int st = 0; st < S_; ++st) {
        const int p = st & 1;
        const _Float16* hb = h_lds[p];

        // ---- VALU h reads (4 distributed b128) + MFMA A reads (8 bcast) ----
        union { h8v v; h2 q[4]; } u0, u1, u2, u3;
        u0.v = *(const h8v*)&hb[vbase];
        u1.v = *(const h8v*)&hb[vbase + 8];
        u2.v = *(const h8v*)&hb[vbase + 16];
        u3.v = *(const h8v*)&hb[vbase + 24];

        h8v af[8];
        #pragma unroll
        for (int ks = 0; ks < 8; ++ks)
            af[ks] = *(const h8v*)&hb[32 * ks + abase];

        // ---- MFMA pipe: 16 MFMA, 2 independent chains ----
        f4 acc0 = {0.f, 0.f, 0.f, 0.f};
        f4 acc1 = {0.f, 0.f, 0.f, 0.f};
        #pragma unroll
        for (int ks = 0; ks < 8; ++ks) {
            acc0 = __builtin_amdgcn_mfma_f32_16x16x32_f16(af[ks], bf[0][ks], acc0, 0, 0, 0);
            acc1 = __builtin_amdgcn_mfma_f32_16x16x32_f16(af[ks], bf[1][ks], acc1, 0, 0, 0);
        }

        // ---- VALU pipe: 64 dot2 into 4 accs (runs while MFMA pipe chews) ----
        float a0 = 0.f, a1 = 0.f, a2 = 0.f, a3 = 0.f;
        #pragma unroll
        for (int m = 0; m < 4; ++m) {
            a0 = fdot2f(u0.q[m], wv[0][m], a0);
            a1 = fdot2f(u0.q[m], wv[1][m], a1);
            a2 = fdot2f(u0.q[m], wv[2][m], a2);
            a3 = fdot2f(u0.q[m], wv[3][m], a3);
        }
        #pragma unroll
        for (int m = 0; m < 4; ++m) {
            a0 = fdot2f(u1.q[m], wv[0][4 + m], a0);
            a1 = fdot2f(u1.q[m], wv[1][4 + m], a1);
            a2 = fdot2f(u1.q[m], wv[2][4 + m], a2);
            a3 = fdot2f(u1.q[m], wv[3][4 + m], a3);
        }
        #pragma unroll
        for (int m = 0; m < 4; ++m) {
            a0 = fdot2f(u2.q[m], wv[0][8 + m], a0);
            a1 = fdot2f(u2.q[m], wv[1][8 + m], a1);
            a2 = fdot2f(u2.q[m], wv[2][8 + m], a2);
            a3 = fdot2f(u2.q[m], wv[3][8 + m], a3);
        }
        #pragma unroll
        for (int m = 0; m < 4; ++m) {
            a0 = fdot2f(u3.q[m], wv[0][12 + m], a0);
            a1 = fdot2f(u3.q[m], wv[1][12 + m], a1);
            a2 = fdot2f(u3.q[m], wv[2][12 + m], a2);
            a3 = fdot2f(u3.q[m], wv[3][12 + m], a3);
        }

        // ---- VALU reduce: butterfly over slices {half_mirror, ^2, ^1} ----
        // stage 1 (lane -> 7-sl3 within 8-group): keep jj&2 == (b2v?2:0)
        float kA = b2v ? a2 : a0, sA = b2v ? a0 : a2;
        float kB = b2v ? a3 : a1, sB = b2v ? a1 : a3;
        kA += dpp_mv<DPP_HMIRR>(sA);
        kB += dpp_mv<DPP_HMIRR>(sB);
        // stage 2 (lane^2): keep jj&1 == b1v
        float nn = b1v ? kB : kA, snd = b1v ? kA : kB;
        nn += dpp_mv<DPP_XOR2>(snd);
        // stage 3 (lane^1): same-col all-reduce
        nn += dpp_mv<DPP_XOR1>(nn);
        // nn = full dot for jv_own

        // ---- epilogues ----
        const float vm = (kg == 1) ? acc1[0] : acc0[0];
        const float preM = vm + xrM[st & 3];
        const float preV = nn + xrV[st & 3];
        const float eM = __builtin_amdgcn_exp2f(preM * 2.8853900817779268f);
        const float eV = __builtin_amdgcn_exp2f(preV * 2.8853900817779268f);
        const float hnM = fmaf(-2.f, __builtin_amdgcn_rcpf(eM + 1.f), 1.f);
        const float hnV = fmaf(-2.f, __builtin_amdgcn_rcpf(eV + 1.f), 1.f);

        if (own_m) {
            outb[(long long)st * H_ + j_m] = hnM;
            h_lds[p ^ 1][j_m] = (_Float16)hnM;
        }
        if (own_v) {
            outb[(long long)st * H_ + jv_own] = hnV;
            h_lds[p ^ 1][jv_own] = (_Float16)hnV;
        }

        const int nt4 = st + 4;
        if (nt4 < S_) {
            xrM[st & 3] = outb[(long long)nt4 * H_ + j_m];
            xrV[st & 3] = outb[(long long)nt4 * H_ + jv_own];
        }
        lds_barrier();
    }
}

extern "C" void kernel_launch(void* const* d_in, const int* in_sizes, int n_in,
                              void* d_out, int out_size, void* d_ws, size_t ws_size,
                              hipStream_t stream) {
    const float* x  = (const float*)d_in[0];   // [B,S,D]
    const float* s0 = (const float*)d_in[1];   // [B,H]
    const float* Wx = (const float*)d_in[2];   // [D,H]
    const float* Wh = (const float*)d_in[3];   // [H,H]
    const float* bv = (const float*)d_in[4];   // [H]
    float* out = (float*)d_out;                // [B,S,H]

    xproj_kernel<<<dim3((B_ * S_) / 32), dim3(256), 0, stream>>>(x, Wx, bv, out);
    scan_kernel<<<dim3(B_), dim3(256), 0, stream>>>(Wh, s0, out);
}

// Round 14
// 1705.496 us; speedup vs baseline: 2.3640x; 2.3640x over previous
//
#include <hip/hip_runtime.h>

#define B_ 16
#define S_ 4096
#define D_ 256
#define H_ 256

typedef _Float16 h2 __attribute__((ext_vector_type(2)));
typedef _Float16 h4 __attribute__((ext_vector_type(4)));
typedef _Float16 h8 __attribute__((ext_vector_type(8)));
typedef _Float16 h8v __attribute__((ext_vector_type(8)));
typedef float f4 __attribute__((ext_vector_type(4)));

static __device__ __forceinline__ float fdot2f(h2 a, h2 b, float c) {
    return __builtin_amdgcn_fdot2(a, b, c, false);
}

template <int CTRL>
static __device__ __forceinline__ float dpp_qp(float v) {
    int r = __builtin_amdgcn_update_dpp(0, __float_as_int(v), CTRL, 0xF, 0xF, true);
    return __int_as_float(r);
}
#define DPP_XOR1 0xB1   // quad_perm [1,0,3,2]
#define DPP_XOR2 0x4E   // quad_perm [2,3,0,1]

// LDS-only barrier: drain LDS ops, NOT vmcnt (T4).
static __device__ __forceinline__ void lds_barrier() {
    asm volatile("s_waitcnt lgkmcnt(0)" ::: "memory");
    __builtin_amdgcn_s_barrier();
}

// swizzled f16-index for h element i in a 256-entry LDS buffer (R4-verified).
static __device__ __forceinline__ int swz(int i) {
    const int s = i >> 6, r = (i >> 3) & 7, e = i & 7;
    return 64 * s + 8 * ((r + 2 * s) & 7) + e;
}

// Kernel 1: xp = x @ Wx + b via MFMA f16 (f32 accumulate), written into d_out.
// 256 blocks x 256 rows. Wave w owns cols [64w,64w+64) with Wx resident in
// registers (B-frag convention verified numerically in rounds 7/11: lane
// (kg,lc) elem e holds W[k=32ks+8kg+e][j=64w+16nt+lc]). Per 16-row iter:
// x tile f32->f16 staged in LDS (stride 272: af reads 2-way-free), A-frag
// row = lc, k-window 8kg (same map as B => permutation-safe). C layout
// (m89): col = lc, row = 4kg+reg. Next x tile prefetched into regs under
// the MFMA compute (T14).
__global__ __launch_bounds__(256, 1) void xproj_kernel(
    const float* __restrict__ x, const float* __restrict__ Wx,
    const float* __restrict__ bias, float* __restrict__ out)
{
    __shared__ __align__(16) _Float16 xs[16 * 272];
    const int tid = threadIdx.x;
    const int l   = tid & 63;
    const int wav = tid >> 6;      // 0..3
    const int lc  = l & 15;
    const int kg  = l >> 4;        // 0..3
    const long long row0 = (long long)blockIdx.x * 256;

    // B-frags in registers: 32 frags = 128 VGPRs (loaded once per block)
    h8v bf[4][8];
    #pragma unroll
    for (int nt = 0; nt < 4; ++nt) {
        const int j = 64 * wav + 16 * nt + lc;
        #pragma unroll
        for (int ks = 0; ks < 8; ++ks) {
            #pragma unroll
            for (int e = 0; e < 8; ++e)
                bf[nt][ks][e] = (_Float16)Wx[(32 * ks + 8 * kg + e) * H_ + j];
        }
    }
    float bvv[4];
    #pragma unroll
    for (int nt = 0; nt < 4; ++nt)
        bvv[nt] = bias[64 * wav + 16 * nt + lc];

    // prefetch iter-0 x tile: thread covers rows wav+4k4, float4 col l
    f4 pre[4];
    #pragma unroll
    for (int k4 = 0; k4 < 4; ++k4)
        pre[k4] = *(const f4*)&x[(row0 + wav + 4 * k4) * D_ + 4 * l];

    for (int it = 0; it < 16; ++it) {
        const long long r0 = row0 + it * 16;

        __syncthreads();   // previous iter's af reads done before overwrite
        #pragma unroll
        for (int k4 = 0; k4 < 4; ++k4) {
            h4 hv;
            hv[0] = (_Float16)pre[k4].x;
            hv[1] = (_Float16)pre[k4].y;
            hv[2] = (_Float16)pre[k4].z;
            hv[3] = (_Float16)pre[k4].w;
            *(h4*)&xs[(wav + 4 * k4) * 272 + 4 * l] = hv;
        }
        __syncthreads();

        // prefetch next tile under compute (T14)
        if (it + 1 < 16) {
            const long long rn = row0 + (it + 1) * 16;
            #pragma unroll
            for (int k4 = 0; k4 < 4; ++k4)
                pre[k4] = *(const f4*)&x[(rn + wav + 4 * k4) * D_ + 4 * l];
        }

        f4 acc[4];
        #pragma unroll
        for (int nt = 0; nt < 4; ++nt)
            acc[nt] = (f4){0.f, 0.f, 0.f, 0.f};

        #pragma unroll
        for (int ks = 0; ks < 8; ++ks) {
            h8v af = *(const h8v*)&xs[lc * 272 + 32 * ks + 8 * kg];
            acc[0] = __builtin_amdgcn_mfma_f32_16x16x32_f16(af, bf[0][ks], acc[0], 0, 0, 0);
            acc[1] = __builtin_amdgcn_mfma_f32_16x16x32_f16(af, bf[1][ks], acc[1], 0, 0, 0);
            acc[2] = __builtin_amdgcn_mfma_f32_16x16x32_f16(af, bf[2][ks], acc[2], 0, 0, 0);
            acc[3] = __builtin_amdgcn_mfma_f32_16x16x32_f16(af, bf[3][ks], acc[3], 0, 0, 0);
        }

        #pragma unroll
        for (int nt = 0; nt < 4; ++nt) {
            const int j = 64 * wav + 16 * nt + lc;
            #pragma unroll
            for (int r = 0; r < 4; ++r)
                out[(r0 + 4 * kg + r) * H_ + j] = acc[nt][r] + bvv[nt];
        }
    }
}

// Kernel 2: sequential scan (round-8 version, best measured: 1679 us).
// One block (CU) per batch, 256 threads. Split-K x4 + DPP quad reduce,
// swizzled h LDS, xp register ring distance 4, lgkm-only barrier.
__global__ __launch_bounds__(256, 1) void scan_kernel(
    const float* __restrict__ Wh, const float* __restrict__ state0,
    float* __restrict__ out)
{
    __shared__ __align__(16) _Float16 hbuf[2][H_];
    const int tid = threadIdx.x;
    const int s = tid & 3;          // i-slice
    const int q = tid >> 2;         // j-group
    const int b = blockIdx.x;
    const bool o1 = (s & 1) != 0;
    const bool o2 = (s & 2) != 0;

    // W[i][j] for i in [64s,64s+64), j in [4q,4q+4), packed as h2 i-pairs.
    h2 w[4][32];
    #pragma unroll
    for (int jj = 0; jj < 4; ++jj) {
        const int j = 4 * q + jj;
        #pragma unroll
        for (int ii = 0; ii < 32; ++ii) {
            const int i = 64 * s + 2 * ii;
            h2 p;
            p[0] = (_Float16)Wh[(long long)i * H_ + j];
            p[1] = (_Float16)Wh[(long long)(i + 1) * H_ + j];
            w[jj][ii] = p;
        }
    }

    hbuf[0][swz(tid)] = (_Float16)state0[b * H_ + tid];

    float* __restrict__ outb = out + (long long)b * S_ * H_;

    // xp prefetch ring, distance 4 (static indices via unroll-4)
    float xr[4];
    #pragma unroll
    for (int k = 0; k < 4; ++k)
        xr[k] = outb[(long long)k * H_ + tid];
    __syncthreads();

    // chunk r holds h[64s+8r .. +8] at f16-pos 64s + 8*((r+2s)&7)
    #pragma unroll 4
    for (int st = 0; st < S_; ++st) {
        const int p = st & 1;
        const _Float16* hb = hbuf[p];

        h8 hv[8];
        #pragma unroll
        for (int r = 0; r < 8; ++r)
            hv[r] = *(const h8*)&hb[64 * s + 8 * ((r + 2 * s) & 7)];

        float acc0 = 0.f, acc1 = 0.f, acc2 = 0.f, acc3 = 0.f;
        #pragma unroll
        for (int r = 0; r < 8; ++r) {
            union { h8 v; h2 pr[4]; } u;
            u.v = hv[r];
            #pragma unroll
            for (int m = 0; m < 4; ++m) {
                const int ii = 4 * r + m;
                acc0 = fdot2f(u.pr[m], w[0][ii], acc0);
                acc1 = fdot2f(u.pr[m], w[1][ii], acc1);
                acc2 = fdot2f(u.pr[m], w[2][ii], acc2);
                acc3 = fdot2f(u.pr[m], w[3][ii], acc3);
            }
        }

        // reduce-scatter across the 4 slice-threads (pure VALU DPP)
        float vA = o1 ? acc1 : acc0;
        float vB = o1 ? acc3 : acc2;
        float sA = o1 ? acc0 : acc1;
        float sB = o1 ? acc2 : acc3;
        vA += dpp_qp<DPP_XOR1>(sA);
        vB += dpp_qp<DPP_XOR1>(sB);
        float v   = o2 ? vB : vA;
        float snd = o2 ? vA : vB;
        v += dpp_qp<DPP_XOR2>(snd);
        // v = full dot for j = 4q + s = tid

        const float pre = v + xr[st & 3];
        const float e = __builtin_amdgcn_exp2f(pre * 2.8853900817779268f);
        const float hn = fmaf(-2.f, __builtin_amdgcn_rcpf(e + 1.f), 1.f);

        outb[(long long)st * H_ + tid] = hn;       // stays in flight
        hbuf[p ^ 1][swz(tid)] = (_Float16)hn;      // publish h for t+1

        const int nt = st + 4;
        xr[st & 3] = (nt < S_) ? outb[(long long)nt * H_ + tid] : 0.f;
        lds_barrier();   // lgkmcnt(0) + s_barrier — NO vmcnt drain
    }
}

extern "C" void kernel_launch(void* const* d_in, const int* in_sizes, int n_in,
                              void* d_out, int out_size, void* d_ws, size_t ws_size,
                              hipStream_t stream) {
    const float* x  = (const float*)d_in[0];   // [B,S,D]
    const float* s0 = (const float*)d_in[1];   // [B,H]
    const float* Wx = (const float*)d_in[2];   // [D,H]
    const float* Wh = (const float*)d_in[3];   // [H,H]
    const float* bv = (const float*)d_in[4];   // [H]
    float* out = (float*)d_out;                // [B,S,H]

    xproj_kernel<<<dim3((B_ * S_) / 256), dim3(256), 0, stream>>>(x, Wx, bv, out);
    scan_kernel<<<dim3(B_), dim3(256), 0, stream>>>(Wh, s0, out);
}